// Round 2
// baseline (2008.999 us; speedup 1.0000x reference)
//
#include <hip/hip_runtime.h>
#include <hip/hip_bf16.h>
#include <math.h>

#define NN 512
#define HH 128
#define INDIM 64
#define BB 256
#define NE 4096               // directed edge count (2*E_UND)
#define MROWS (BB*NN)         // 131072
#define OUT0 (BB*NN*HH)       // 16777216 floats, start of C in d_out

// ---------------------------------------------------------------------------
// C = softmax(logits,-1) * adj * dir; C /= max(rowsum, 1e-8)
// one block per row (512 blocks x 256 threads, 2 elements/thread)
// ---------------------------------------------------------------------------
__global__ __launch_bounds__(256) void k_causalC(
    const float* __restrict__ logits, const float* __restrict__ adj,
    const float* __restrict__ dir, float* __restrict__ Cout)
{
  const int row = blockIdx.x;
  const int t = threadIdx.x;
  __shared__ float red[256];
  const float* lrow = logits + (size_t)row * NN;
  float v0 = lrow[t], v1 = lrow[t + 256];
  float mx = fmaxf(v0, v1);
  red[t] = mx; __syncthreads();
  for (int s = 128; s > 0; s >>= 1) { if (t < s) red[t] = fmaxf(red[t], red[t + s]); __syncthreads(); }
  mx = red[0]; __syncthreads();
  float e0 = __expf(v0 - mx), e1 = __expf(v1 - mx);
  red[t] = e0 + e1; __syncthreads();
  for (int s = 128; s > 0; s >>= 1) { if (t < s) red[t] += red[t + s]; __syncthreads(); }
  float sumE = red[0]; __syncthreads();
  float m0 = adj[(size_t)row * NN + t] * dir[(size_t)row * NN + t];
  float m1 = adj[(size_t)row * NN + t + 256] * dir[(size_t)row * NN + t + 256];
  float me0 = e0 * m0, me1 = e1 * m1;
  red[t] = me0 + me1; __syncthreads();
  for (int s = 128; s > 0; s >>= 1) { if (t < s) red[t] += red[t + s]; __syncthreads(); }
  float sumME = red[0];
  float sm = sumME / sumE;                   // C row-sum before renorm
  float denom = fmaxf(sm, 1e-8f) * sumE;     // (me/sumE)/clip == me/denom
  Cout[(size_t)row * NN + t]       = me0 / denom;
  Cout[(size_t)row * NN + t + 256] = me1 / denom;
}

// ---------------------------------------------------------------------------
// Generic fp32 GEMM: Out(M,128) = [opt relu]( A(M,KD) @ W(KD,128) + bias [+ Out] )
// 32-row tiles, K in 64-chunks staged in LDS, 4x4 register micro-tile.
// NOTE: no __restrict__ on A/Out — we call this IN-PLACE (Out==A). Safe because
// each block stages its tile's A rows into LDS fully before storing the same
// rows, and tiles are block-disjoint (grid-stride).
// ---------------------------------------------------------------------------
template<int KD, bool RELU, bool ACCUM>
__global__ __launch_bounds__(256) void k_gemm(
    const float* A, const float* __restrict__ W,
    const float* __restrict__ bias, float* Out, int ntiles)
{
  __shared__ float Wl[64 * 128];
  __shared__ float Al[32 * 68];        // stride 68 floats (pad 4) keeps f4 align
  const int t = threadIdx.x;
  const int tc = t & 31, tr = t >> 5;
  const int c0 = tc * 4, r0 = tr * 4;
  float bx = 0, by = 0, bz = 0, bw = 0;
  if (bias) { bx = bias[c0]; by = bias[c0 + 1]; bz = bias[c0 + 2]; bw = bias[c0 + 3]; }
  for (int tile = blockIdx.x; tile < ntiles; tile += gridDim.x) {
    const int rowbase = tile * 32;
    float acc[4][4] = {};
    for (int kc = 0; kc < KD; kc += 64) {
      __syncthreads();                 // protect LDS from previous compute
      for (int i = t; i < 64 * 32; i += 256)
        ((float4*)Wl)[i] = ((const float4*)(W + (size_t)kc * 128))[i];
      for (int i = t; i < 32 * 16; i += 256) {
        int r = i >> 4, seg = i & 15;
        *(float4*)&Al[r * 68 + seg * 4] =
            *(const float4*)&A[(size_t)(rowbase + r) * KD + kc + seg * 4];
      }
      __syncthreads();
      #pragma unroll
      for (int k = 0; k < 64; k += 4) {
        float aR[4][4], wR[4][4];
        #pragma unroll
        for (int i = 0; i < 4; i++) {
          float4 av = *(float4*)&Al[(r0 + i) * 68 + k];
          aR[i][0] = av.x; aR[i][1] = av.y; aR[i][2] = av.z; aR[i][3] = av.w;
        }
        #pragma unroll
        for (int kk = 0; kk < 4; kk++) {
          float4 wv = *(float4*)&Wl[(k + kk) * 128 + c0];
          wR[kk][0] = wv.x; wR[kk][1] = wv.y; wR[kk][2] = wv.z; wR[kk][3] = wv.w;
        }
        #pragma unroll
        for (int i = 0; i < 4; i++)
          #pragma unroll
          for (int kk = 0; kk < 4; kk++)
            #pragma unroll
            for (int j = 0; j < 4; j++)
              acc[i][j] = fmaf(aR[i][kk], wR[kk][j], acc[i][j]);
      }
    }
    #pragma unroll
    for (int i = 0; i < 4; i++) {
      size_t row = (size_t)rowbase + r0 + i;
      float4 o;
      o.x = acc[i][0] + bx; o.y = acc[i][1] + by;
      o.z = acc[i][2] + bz; o.w = acc[i][3] + bw;
      if (ACCUM) {
        float4 prev = *(float4*)&Out[row * 128 + c0];
        o.x += prev.x; o.y += prev.y; o.z += prev.z; o.w += prev.w;
      }
      if (RELU) {
        o.x = fmaxf(o.x, 0.f); o.y = fmaxf(o.y, 0.f);
        o.z = fmaxf(o.z, 0.f); o.w = fmaxf(o.w, 0.f);
      }
      *(float4*)&Out[row * 128 + c0] = o;
    }
  }
}

// ---------------------------------------------------------------------------
// Graph prep (single block, 512 threads): in-degree (+self), dinv, CSR by dst
// ---------------------------------------------------------------------------
__global__ __launch_bounds__(512) void k_graph(
    const int* __restrict__ ei, float* __restrict__ dinv,
    int* __restrict__ roff, int* __restrict__ col, float* __restrict__ wn)
{
  __shared__ int scnt[512];
  __shared__ int sscan[512];
  __shared__ float sdinv[512];
  __shared__ int scur[512];
  const int t = threadIdx.x;
  const int* src = ei;
  const int* dst = ei + NE;
  scnt[t] = 0; __syncthreads();
  for (int e = t; e < NE; e += 512) atomicAdd(&scnt[dst[e]], 1);
  __syncthreads();
  int myc = scnt[t];
  float di = rsqrtf((float)(myc + 1));     // +1 self loop
  sdinv[t] = di; dinv[t] = di;
  sscan[t] = myc; __syncthreads();
  for (int s = 1; s < 512; s <<= 1) {      // Hillis-Steele inclusive scan
    int v = (t >= s) ? sscan[t - s] : 0;
    __syncthreads();
    sscan[t] += v;
    __syncthreads();
  }
  int excl = sscan[t] - myc;
  roff[t] = excl;
  if (t == 511) roff[512] = sscan[511];
  scur[t] = excl; __syncthreads();
  for (int e = t; e < NE; e += 512) {
    int d = dst[e], s = src[e];
    int pos = atomicAdd(&scur[d], 1);
    col[pos] = s;
    wn[pos] = sdinv[s] * sdinv[d];
  }
}

// ---------------------------------------------------------------------------
// Flash-style masked causal attention.
// block = (batch, 32 q-rows); loop 16 key tiles of 32.
// out = sum_j p_ij C_ij V_j / (sum pC + 1e-8 * sum p), p = exp(S - m)
// NOTE: no __restrict__ on Q/Oc — called with Oc == Q (in-place). Safe: each
// block reads only its own 32 Q rows (staged to LDS at entry) and writes only
// those rows at exit.
// ---------------------------------------------------------------------------
__global__ __launch_bounds__(256) void k_attn(
    const float* Q, const float* __restrict__ Km,
    const float* __restrict__ Vm, const float* __restrict__ C,
    float* Oc)
{
  const int b = blockIdx.x >> 4;
  const int q0 = (blockIdx.x & 15) * 32;
  __shared__ float Qs[32][132];
  __shared__ float Ks[32][132];
  __shared__ float Vs[32][132];
  __shared__ float Ss[32][33];
  __shared__ float Cs[32][33];
  __shared__ float mrow[32], serow[32], secrow[32], arow[32];
  const int t = threadIdx.x;
  const int tc = t & 31, tr = t >> 5;
  const int c0 = tc * 4, r0 = tr * 4;
  const int tq = (t >> 4) * 2, tk = (t & 15) * 2;
  const float* Qb = Q + ((size_t)b * NN + q0) * HH;
  for (int i = t; i < 32 * 32; i += 256) {
    int r = i >> 5, seg = i & 31;
    *(float4*)&Qs[r][seg * 4] = *(const float4*)&Qb[(size_t)r * HH + seg * 4];
  }
  if (t < 32) { mrow[t] = -INFINITY; serow[t] = 0.f; secrow[t] = 0.f; }
  float acc[4][4] = {};
  const float scale = 0.088388347648318447f;   // 1/sqrt(128)
  for (int kt = 0; kt < 16; kt++) {
    const int k0 = kt * 32;
    __syncthreads();                           // LDS reuse fence
    const float* Kb = Km + ((size_t)b * NN + k0) * HH;
    const float* Vb = Vm + ((size_t)b * NN + k0) * HH;
    for (int i = t; i < 32 * 32; i += 256) {
      int r = i >> 5, seg = i & 31;
      *(float4*)&Ks[r][seg * 4] = *(const float4*)&Kb[(size_t)r * HH + seg * 4];
      *(float4*)&Vs[r][seg * 4] = *(const float4*)&Vb[(size_t)r * HH + seg * 4];
    }
    for (int i = t; i < 32 * 32; i += 256) {
      int r = i >> 5, cc = i & 31;
      Cs[r][cc] = C[(size_t)(q0 + r) * NN + k0 + cc];
    }
    __syncthreads();
    // S = Q K^T (2x2 scores per thread)
    float s00 = 0, s01 = 0, s10 = 0, s11 = 0;
    #pragma unroll
    for (int d = 0; d < HH; d += 4) {
      float4 qa = *(float4*)&Qs[tq][d];
      float4 qc = *(float4*)&Qs[tq + 1][d];
      float4 ka = *(float4*)&Ks[tk][d];
      float4 kc = *(float4*)&Ks[tk + 1][d];
      s00 = fmaf(qa.x, ka.x, fmaf(qa.y, ka.y, fmaf(qa.z, ka.z, fmaf(qa.w, ka.w, s00))));
      s01 = fmaf(qa.x, kc.x, fmaf(qa.y, kc.y, fmaf(qa.z, kc.z, fmaf(qa.w, kc.w, s01))));
      s10 = fmaf(qc.x, ka.x, fmaf(qc.y, ka.y, fmaf(qc.z, ka.z, fmaf(qc.w, ka.w, s10))));
      s11 = fmaf(qc.x, kc.x, fmaf(qc.y, kc.y, fmaf(qc.z, kc.z, fmaf(qc.w, kc.w, s11))));
    }
    Ss[tq][tk]     = s00 * scale;
    Ss[tq][tk + 1] = s01 * scale;
    Ss[tq + 1][tk]     = s10 * scale;
    Ss[tq + 1][tk + 1] = s11 * scale;
    __syncthreads();
    // online softmax state update: 8 threads per q-row
    {
      const int row = t >> 3, j = t & 7;
      float x0 = Ss[row][j * 4 + 0], x1 = Ss[row][j * 4 + 1];
      float x2 = Ss[row][j * 4 + 2], x3 = Ss[row][j * 4 + 3];
      float lm = fmaxf(fmaxf(x0, x1), fmaxf(x2, x3));
      lm = fmaxf(lm, __shfl_xor(lm, 1));
      lm = fmaxf(lm, __shfl_xor(lm, 2));
      lm = fmaxf(lm, __shfl_xor(lm, 4));
      float mold = mrow[row];
      float mnew = fmaxf(mold, lm);
      float p0 = __expf(x0 - mnew), p1 = __expf(x1 - mnew);
      float p2 = __expf(x2 - mnew), p3 = __expf(x3 - mnew);
      float g0 = Cs[row][j * 4 + 0], g1 = Cs[row][j * 4 + 1];
      float g2 = Cs[row][j * 4 + 2], g3 = Cs[row][j * 4 + 3];
      float pc0 = p0 * g0, pc1 = p1 * g1, pc2 = p2 * g2, pc3 = p3 * g3;
      float sp = (p0 + p1) + (p2 + p3);
      float spc = (pc0 + pc1) + (pc2 + pc3);
      sp += __shfl_xor(sp, 1); sp += __shfl_xor(sp, 2); sp += __shfl_xor(sp, 4);
      spc += __shfl_xor(spc, 1); spc += __shfl_xor(spc, 2); spc += __shfl_xor(spc, 4);
      Ss[row][j * 4 + 0] = pc0; Ss[row][j * 4 + 1] = pc1;
      Ss[row][j * 4 + 2] = pc2; Ss[row][j * 4 + 3] = pc3;
      if (j == 0) {
        float al = __expf(mold - mnew);        // exp(-inf)=0 on first tile
        arow[row] = al; mrow[row] = mnew;
        serow[row] = serow[row] * al + sp;
        secrow[row] = secrow[row] * al + spc;
      }
    }
    __syncthreads();
    // O = O*alpha + (p*C) @ V
    float a0 = arow[r0 + 0], a1 = arow[r0 + 1], a2 = arow[r0 + 2], a3 = arow[r0 + 3];
    #pragma unroll
    for (int j = 0; j < 4; j++) { acc[0][j] *= a0; acc[1][j] *= a1; acc[2][j] *= a2; acc[3][j] *= a3; }
    #pragma unroll
    for (int kk = 0; kk < 32; kk++) {
      float p0 = Ss[r0 + 0][kk], p1 = Ss[r0 + 1][kk];
      float p2 = Ss[r0 + 2][kk], p3 = Ss[r0 + 3][kk];
      float4 v = *(float4*)&Vs[kk][c0];
      acc[0][0] = fmaf(p0, v.x, acc[0][0]); acc[0][1] = fmaf(p0, v.y, acc[0][1]);
      acc[0][2] = fmaf(p0, v.z, acc[0][2]); acc[0][3] = fmaf(p0, v.w, acc[0][3]);
      acc[1][0] = fmaf(p1, v.x, acc[1][0]); acc[1][1] = fmaf(p1, v.y, acc[1][1]);
      acc[1][2] = fmaf(p1, v.z, acc[1][2]); acc[1][3] = fmaf(p1, v.w, acc[1][3]);
      acc[2][0] = fmaf(p2, v.x, acc[2][0]); acc[2][1] = fmaf(p2, v.y, acc[2][1]);
      acc[2][2] = fmaf(p2, v.z, acc[2][2]); acc[2][3] = fmaf(p2, v.w, acc[2][3]);
      acc[3][0] = fmaf(p3, v.x, acc[3][0]); acc[3][1] = fmaf(p3, v.y, acc[3][1]);
      acc[3][2] = fmaf(p3, v.z, acc[3][2]); acc[3][3] = fmaf(p3, v.w, acc[3][3]);
    }
  }
  __syncthreads();
  #pragma unroll
  for (int i = 0; i < 4; i++) {
    int r = r0 + i;
    float inv = 1.0f / (secrow[r] + 1e-8f * serow[r]);
    float4 o;
    o.x = acc[i][0] * inv; o.y = acc[i][1] * inv;
    o.z = acc[i][2] * inv; o.w = acc[i][3] * inv;
    *(float4*)&Oc[((size_t)b * NN + q0 + r) * HH + c0] = o;
  }
}

// ---------------------------------------------------------------------------
// GCN gather: out[b,i,:] = relu( sum_nbr hW[b,src,:]*wn + hW[b,i,:]*dinv_i^2 + bias )
// block = 2 (b,i) rows, thread = one channel
// ---------------------------------------------------------------------------
__global__ __launch_bounds__(256) void k_gather(
    const float* __restrict__ hW, const float* __restrict__ bias,
    const int* __restrict__ roff, const int* __restrict__ col,
    const float* __restrict__ wn, const float* __restrict__ dinv,
    float* __restrict__ out)
{
  const int t = threadIdx.x;
  const size_t idx = (size_t)blockIdx.x * 2 + (t >> 7);
  const int c = t & 127;
  const int b = (int)(idx >> 9);
  const int i = (int)(idx & 511);
  const float* base = hW + (size_t)b * NN * HH;
  float di = dinv[i];
  float acc = base[(size_t)i * HH + c] * di * di;
  int p0 = roff[i], p1 = roff[i + 1];
  for (int p = p0; p < p1; p++)
    acc = fmaf(base[(size_t)col[p] * HH + c], wn[p], acc);
  acc += bias[c];
  out[idx * HH + c] = fmaxf(acc, 0.f);
}

// ---------------------------------------------------------------------------
// LayerNorm over H=128 + affine
// ---------------------------------------------------------------------------
__global__ __launch_bounds__(256) void k_ln(
    const float* __restrict__ X, const float* __restrict__ g,
    const float* __restrict__ bt, float* __restrict__ out)
{
  const int t = threadIdx.x;
  const size_t row = (size_t)blockIdx.x * 2 + (t >> 7);
  const int c = t & 127;
  const int hr = t >> 7;
  __shared__ float red[2][128];
  float v = X[row * HH + c];
  red[hr][c] = v; __syncthreads();
  for (int s = 64; s > 0; s >>= 1) { if (c < s) red[hr][c] += red[hr][c + s]; __syncthreads(); }
  float mu = red[hr][0] * (1.0f / 128.0f);
  __syncthreads();
  float d = v - mu;
  red[hr][c] = d * d; __syncthreads();
  for (int s = 64; s > 0; s >>= 1) { if (c < s) red[hr][c] += red[hr][c + s]; __syncthreads(); }
  float var = red[hr][0] * (1.0f / 128.0f);
  float inv = rsqrtf(var + 1e-5f);
  out[row * HH + c] = d * inv * g[c] + bt[c];
}

// ---------------------------------------------------------------------------
// Buffer schedule (3 x 64MB ws slots + d_out scratch; ~201 MB total ws):
//   h->ws0 ; hW->ws1 ; g1->ws2 ; hW2->ws1 ; g2->ws2 ;
//   comb=g2@Wf_bot+bf->ws1 ; Q->ws2 ; K->outp ; V->ws0 (in-place over h) ;
//   attn->ws2 (in-place over Q) ; comb+=hc@Wf_top ; LN(ws1)->outp
// ---------------------------------------------------------------------------
extern "C" void kernel_launch(void* const* d_in, const int* in_sizes, int n_in,
                              void* d_out, int out_size, void* d_ws, size_t ws_size,
                              hipStream_t stream)
{
  const float* x     = (const float*)d_in[0];
  const int*   ei    = (const int*)d_in[1];
  const float* adj   = (const float*)d_in[2];
  const float* dmask = (const float*)d_in[3];
  const float* clog  = (const float*)d_in[4];
  const float* W_in  = (const float*)d_in[5];
  const float* b_in  = (const float*)d_in[6];
  const float* Wq    = (const float*)d_in[7];
  const float* bq    = (const float*)d_in[8];
  const float* Wk    = (const float*)d_in[9];
  const float* bk    = (const float*)d_in[10];
  const float* Wv    = (const float*)d_in[11];
  const float* bv    = (const float*)d_in[12];
  const float* gcnW  = (const float*)d_in[13];
  const float* gcnB  = (const float*)d_in[14];
  const float* Wf    = (const float*)d_in[15];
  const float* bf    = (const float*)d_in[16];
  const float* lng   = (const float*)d_in[17];
  const float* lnb   = (const float*)d_in[18];

  float* outp = (float*)d_out;
  float* Cmat = outp + OUT0;              // C is output[1], lives in d_out

  float* F = (float*)d_ws;
  const size_t BUF = (size_t)OUT0;        // 64MB each
  float* ws0  = F;
  float* ws1  = F + BUF;
  float* ws2  = F + 2 * BUF;
  float* dinv = F + 3 * BUF;
  float* wn   = dinv + 512;
  int*   roff = (int*)(wn + NE);
  int*   col  = roff + 516;               // 513 used, pad to 516

  const int ntiles = MROWS / 32;          // 4096

  // C matrix (also an output) + graph CSR (independent)
  k_causalC<<<512, 256, 0, stream>>>(clog, adj, dmask, Cmat);
  k_graph<<<1, 512, 0, stream>>>(ei, dinv, roff, col, wn);
  // h = relu(x @ W_in + b_in)
  k_gemm<64, true, false><<<1024, 256, 0, stream>>>(x, W_in, b_in, ws0, ntiles);
  // GCN layer 0
  k_gemm<128, false, false><<<1024, 256, 0, stream>>>(ws0, gcnW, nullptr, ws1, ntiles);
  k_gather<<<MROWS / 2, 256, 0, stream>>>(ws1, gcnB, roff, col, wn, dinv, ws2);
  // GCN layer 1
  k_gemm<128, false, false><<<1024, 256, 0, stream>>>(ws2, gcnW + HH * HH, nullptr, ws1, ntiles);
  k_gather<<<MROWS / 2, 256, 0, stream>>>(ws1, gcnB + HH, roff, col, wn, dinv, ws2);
  // partial fuse: comb = g2 @ Wf_bot + bf  -> ws1
  k_gemm<128, false, false><<<1024, 256, 0, stream>>>(ws2, Wf + HH * HH, bf, ws1, ntiles);
  // Q,K,V (V in-place over h)
  k_gemm<128, false, false><<<1024, 256, 0, stream>>>(ws0, Wq, bq, ws2, ntiles);
  k_gemm<128, false, false><<<1024, 256, 0, stream>>>(ws0, Wk, bk, outp, ntiles);
  k_gemm<128, false, false><<<1024, 256, 0, stream>>>(ws0, Wv, bv, ws0, ntiles);
  // attention -> hc (in-place over Q in ws2)
  k_attn<<<BB * 16, 256, 0, stream>>>(ws2, outp, ws0, Cmat, ws2);
  // comb += hc @ Wf_top
  k_gemm<128, false, true><<<1024, 256, 0, stream>>>(ws2, Wf, nullptr, ws1, ntiles);
  // layernorm -> out
  k_ln<<<MROWS / 2, 256, 0, stream>>>(ws1, lng, lnb, outp);
}

// Round 3
// 1334.219 us; speedup vs baseline: 1.5057x; 1.5057x over previous
//
#include <hip/hip_runtime.h>
#include <hip/hip_bf16.h>
#include <math.h>

#define NN 512
#define HH 128
#define INDIM 64
#define BB 256
#define NE 4096               // directed edge count (2*E_UND)
#define MROWS (BB*NN)         // 131072
#define OUT0 (BB*NN*HH)       // 16777216 floats, start of C in d_out

typedef __attribute__((ext_vector_type(8))) short short8v;
typedef __attribute__((ext_vector_type(4))) float float4v;

__device__ __forceinline__ unsigned short f2bf(float f) {
  unsigned u = __float_as_uint(f);
  unsigned r = (u + 0x7fffu + ((u >> 16) & 1u)) >> 16;   // RNE
  return (unsigned short)r;
}

// ---------------------------------------------------------------------------
// C = softmax(logits,-1) * adj * dir; C /= max(rowsum, 1e-8)
// ---------------------------------------------------------------------------
__global__ __launch_bounds__(256) void k_causalC(
    const float* __restrict__ logits, const float* __restrict__ adj,
    const float* __restrict__ dir, float* __restrict__ Cout)
{
  const int row = blockIdx.x;
  const int t = threadIdx.x;
  __shared__ float red[256];
  const float* lrow = logits + (size_t)row * NN;
  float v0 = lrow[t], v1 = lrow[t + 256];
  float mx = fmaxf(v0, v1);
  red[t] = mx; __syncthreads();
  for (int s = 128; s > 0; s >>= 1) { if (t < s) red[t] = fmaxf(red[t], red[t + s]); __syncthreads(); }
  mx = red[0]; __syncthreads();
  float e0 = __expf(v0 - mx), e1 = __expf(v1 - mx);
  red[t] = e0 + e1; __syncthreads();
  for (int s = 128; s > 0; s >>= 1) { if (t < s) red[t] += red[t + s]; __syncthreads(); }
  float sumE = red[0]; __syncthreads();
  float m0 = adj[(size_t)row * NN + t] * dir[(size_t)row * NN + t];
  float m1 = adj[(size_t)row * NN + t + 256] * dir[(size_t)row * NN + t + 256];
  float me0 = e0 * m0, me1 = e1 * m1;
  red[t] = me0 + me1; __syncthreads();
  for (int s = 128; s > 0; s >>= 1) { if (t < s) red[t] += red[t + s]; __syncthreads(); }
  float sumME = red[0];
  float sm = sumME / sumE;
  float denom = fmaxf(sm, 1e-8f) * sumE;
  Cout[(size_t)row * NN + t]       = me0 / denom;
  Cout[(size_t)row * NN + t + 256] = me1 / denom;
}

// ---------------------------------------------------------------------------
// fp32 GEMM: Out(M,128) = [relu]( A(M,KD) @ W(KD,128) + bias [+ Out] )
// OMODE: 0 = fp32 row-major; 1 = bf16 row-major; 2 = bf16 transposed-per-batch
//        (Vt layout: out[(b*128 + c)*512 + node], row = b*512+node)
// ---------------------------------------------------------------------------
template<int KD, bool RELU, bool ACCUM, int OMODE>
__global__ __launch_bounds__(256) void k_gemm(
    const float* A, const float* __restrict__ W,
    const float* __restrict__ bias, float* Out, int ntiles)
{
  __shared__ float Wl[64 * 128];
  __shared__ float Al[32 * 68];
  const int t = threadIdx.x;
  const int tc = t & 31, tr = t >> 5;
  const int c0 = tc * 4, r0 = tr * 4;
  float bx = 0, by = 0, bz = 0, bw = 0;
  if (bias) { bx = bias[c0]; by = bias[c0 + 1]; bz = bias[c0 + 2]; bw = bias[c0 + 3]; }
  for (int tile = blockIdx.x; tile < ntiles; tile += gridDim.x) {
    const int rowbase = tile * 32;
    float acc[4][4] = {};
    for (int kc = 0; kc < KD; kc += 64) {
      __syncthreads();
      for (int i = t; i < 64 * 32; i += 256)
        ((float4*)Wl)[i] = ((const float4*)(W + (size_t)kc * 128))[i];
      for (int i = t; i < 32 * 16; i += 256) {
        int r = i >> 4, seg = i & 15;
        *(float4*)&Al[r * 68 + seg * 4] =
            *(const float4*)&A[(size_t)(rowbase + r) * KD + kc + seg * 4];
      }
      __syncthreads();
      #pragma unroll
      for (int k = 0; k < 64; k += 4) {
        float aR[4][4], wR[4][4];
        #pragma unroll
        for (int i = 0; i < 4; i++) {
          float4 av = *(float4*)&Al[(r0 + i) * 68 + k];
          aR[i][0] = av.x; aR[i][1] = av.y; aR[i][2] = av.z; aR[i][3] = av.w;
        }
        #pragma unroll
        for (int kk = 0; kk < 4; kk++) {
          float4 wv = *(float4*)&Wl[(k + kk) * 128 + c0];
          wR[kk][0] = wv.x; wR[kk][1] = wv.y; wR[kk][2] = wv.z; wR[kk][3] = wv.w;
        }
        #pragma unroll
        for (int i = 0; i < 4; i++)
          #pragma unroll
          for (int kk = 0; kk < 4; kk++)
            #pragma unroll
            for (int j = 0; j < 4; j++)
              acc[i][j] = fmaf(aR[i][kk], wR[kk][j], acc[i][j]);
      }
    }
    #pragma unroll
    for (int i = 0; i < 4; i++) {
      size_t row = (size_t)rowbase + r0 + i;
      float o[4];
      o[0] = acc[i][0] + bx; o[1] = acc[i][1] + by;
      o[2] = acc[i][2] + bz; o[3] = acc[i][3] + bw;
      if (OMODE == 0) {
        if (ACCUM) {
          float4 prev = *(float4*)&Out[row * 128 + c0];
          o[0] += prev.x; o[1] += prev.y; o[2] += prev.z; o[3] += prev.w;
        }
        if (RELU) {
          o[0] = fmaxf(o[0], 0.f); o[1] = fmaxf(o[1], 0.f);
          o[2] = fmaxf(o[2], 0.f); o[3] = fmaxf(o[3], 0.f);
        }
        float4 ov; ov.x = o[0]; ov.y = o[1]; ov.z = o[2]; ov.w = o[3];
        *(float4*)&Out[row * 128 + c0] = ov;
      } else if (OMODE == 1) {
        unsigned short* Ob = (unsigned short*)Out;
        uint2 pk;
        pk.x = (unsigned)f2bf(o[0]) | ((unsigned)f2bf(o[1]) << 16);
        pk.y = (unsigned)f2bf(o[2]) | ((unsigned)f2bf(o[3]) << 16);
        *(uint2*)&Ob[row * 128 + c0] = pk;
      } else {
        unsigned short* Ob = (unsigned short*)Out;
        int b = (int)(row >> 9), node = (int)(row & 511);
        #pragma unroll
        for (int j = 0; j < 4; j++)
          Ob[((size_t)(b * 128 + c0 + j)) * 512 + node] = f2bf(o[j]);
      }
    }
  }
}

// ---------------------------------------------------------------------------
// Graph prep (single block): in-degree (+self), dinv, CSR by dst
// ---------------------------------------------------------------------------
__global__ __launch_bounds__(512) void k_graph(
    const int* __restrict__ ei, float* __restrict__ dinv,
    int* __restrict__ roff, int* __restrict__ col, float* __restrict__ wn)
{
  __shared__ int scnt[512];
  __shared__ int sscan[512];
  __shared__ float sdinv[512];
  __shared__ int scur[512];
  const int t = threadIdx.x;
  const int* src = ei;
  const int* dst = ei + NE;
  scnt[t] = 0; __syncthreads();
  for (int e = t; e < NE; e += 512) atomicAdd(&scnt[dst[e]], 1);
  __syncthreads();
  int myc = scnt[t];
  float di = rsqrtf((float)(myc + 1));
  sdinv[t] = di; dinv[t] = di;
  sscan[t] = myc; __syncthreads();
  for (int s = 1; s < 512; s <<= 1) {
    int v = (t >= s) ? sscan[t - s] : 0;
    __syncthreads();
    sscan[t] += v;
    __syncthreads();
  }
  int excl = sscan[t] - myc;
  roff[t] = excl;
  if (t == 511) roff[512] = sscan[511];
  scur[t] = excl; __syncthreads();
  for (int e = t; e < NE; e += 512) {
    int d = dst[e], s = src[e];
    int pos = atomicAdd(&scur[d], 1);
    col[pos] = s;
    wn[pos] = sdinv[s] * sdinv[d];
  }
}

// ---------------------------------------------------------------------------
// MFMA flash attention (bf16 QK^T and PV, fp32 softmax state).
// block = 4 waves; wave owns 16 q rows; block covers 64 q rows of one batch.
// grid = BB * 8. Key tiles of 64 staged in LDS (K row-major, V transposed).
// out = sum_j p_ij C_ij V_j / (sum pC + 1e-8 sum p), p = exp(S - m)
// MFMA 16x16x32 layouts (verified): A[m=lane&15][k=quad*8+j],
// B[k=quad*8+j][n=lane&15], C/D[row=quad*4+reg][col=lane&15].
// ---------------------------------------------------------------------------
__global__ __launch_bounds__(256) void k_attn_mfma(
    const unsigned short* __restrict__ Qbf, const unsigned short* __restrict__ Kbf,
    const unsigned short* __restrict__ Vtbf, const float* __restrict__ C,
    float* __restrict__ Oc)
{
  const int b = blockIdx.x >> 3;
  const int qblk = blockIdx.x & 7;
  const int t = threadIdx.x;
  const int wave = t >> 6, lane = t & 63;
  const int l15 = lane & 15, quad = lane >> 4;
  const int q0w = qblk * 64 + wave * 16;

  // LDS: padded row strides (units of 8 bf16 = 16B) to break power-of-2 banks
  __shared__ short Ksh[64 * 17 * 8];        // [key][d/8] stride 17
  __shared__ short Vtsh[128 * 9 * 8];       // [d][key/8] stride 9
  __shared__ short Psh[4 * 16 * 9 * 8];     // per wave: [q][key/8] stride 9
  short* Pw = Psh + wave * (16 * 9 * 8);

  // Q fragments: 4 d-chunks of 32
  short8v qf[4];
  #pragma unroll
  for (int dc = 0; dc < 4; dc++)
    qf[dc] = *(const short8v*)&Qbf[((size_t)(b * NN + q0w + l15)) * HH + dc * 32 + quad * 8];

  float m_r[4], sp_r[4], spc_r[4];
  #pragma unroll
  for (int r = 0; r < 4; r++) { m_r[r] = -INFINITY; sp_r[r] = 0.f; spc_r[r] = 0.f; }
  float4v oacc[8];
  #pragma unroll
  for (int dn = 0; dn < 8; dn++) oacc[dn] = (float4v){0.f, 0.f, 0.f, 0.f};

  const float scale = 0.088388347648318447f;   // 1/sqrt(128)

  for (int kt = 0; kt < 8; kt++) {
    const int k0 = kt * 64;
    __syncthreads();
    // stage K tile: 64 keys x 128 d
    for (int i = t; i < 64 * 16; i += 256) {
      int row = i >> 4, seg = i & 15;
      *(short8v*)&Ksh[(row * 17 + seg) * 8] =
          *(const short8v*)&Kbf[((size_t)(b * NN + k0 + row)) * HH + seg * 8];
    }
    // stage Vt tile: 128 d x 64 keys
    for (int i = t; i < 128 * 8; i += 256) {
      int row = i >> 3, seg = i & 7;
      *(short8v*)&Vtsh[(row * 9 + seg) * 8] =
          *(const short8v*)&Vtbf[((size_t)(b * HH + row)) * NN + k0 + seg * 8];
    }
    __syncthreads();

    // C values for this tile (L2-resident, 1MB matrix)
    float cv[4][4];
    #pragma unroll
    for (int n = 0; n < 4; n++)
      #pragma unroll
      for (int r = 0; r < 4; r++)
        cv[n][r] = C[(size_t)(q0w + quad * 4 + r) * NN + k0 + n * 16 + l15];

    // S = Q K^T : 4 key subtiles x 4 d-chunks
    float4v sacc[4];
    #pragma unroll
    for (int n = 0; n < 4; n++) {
      sacc[n] = (float4v){0.f, 0.f, 0.f, 0.f};
      #pragma unroll
      for (int dc = 0; dc < 4; dc++) {
        short8v kf = *(const short8v*)&Ksh[((n * 16 + l15) * 17 + dc * 4 + quad) * 8];
        sacc[n] = __builtin_amdgcn_mfma_f32_16x16x32_bf16(qf[dc], kf, sacc[n], 0, 0, 0);
      }
    }

    // online softmax update
    float sv[4][4], lm[4];
    #pragma unroll
    for (int r = 0; r < 4; r++) lm[r] = -INFINITY;
    #pragma unroll
    for (int n = 0; n < 4; n++)
      #pragma unroll
      for (int r = 0; r < 4; r++) {
        float s = sacc[n][r] * scale;
        sv[n][r] = s;
        lm[r] = fmaxf(lm[r], s);
      }
    #pragma unroll
    for (int r = 0; r < 4; r++) {
      lm[r] = fmaxf(lm[r], __shfl_xor(lm[r], 1));
      lm[r] = fmaxf(lm[r], __shfl_xor(lm[r], 2));
      lm[r] = fmaxf(lm[r], __shfl_xor(lm[r], 4));
      lm[r] = fmaxf(lm[r], __shfl_xor(lm[r], 8));
    }
    float alpha[4];
    #pragma unroll
    for (int r = 0; r < 4; r++) {
      float mnew = fmaxf(m_r[r], lm[r]);
      alpha[r] = __expf(m_r[r] - mnew);
      m_r[r] = mnew;
    }
    float spl[4] = {0.f, 0.f, 0.f, 0.f}, spcl[4] = {0.f, 0.f, 0.f, 0.f};
    #pragma unroll
    for (int n = 0; n < 4; n++)
      #pragma unroll
      for (int r = 0; r < 4; r++) {
        float p = __expf(sv[n][r] - m_r[r]);
        float pcv = p * cv[n][r];
        spl[r] += p; spcl[r] += pcv;
        Pw[(quad * 4 + r) * 72 + n * 16 + l15] = (short)f2bf(pcv);
      }
    #pragma unroll
    for (int r = 0; r < 4; r++) {
      spl[r]  += __shfl_xor(spl[r], 1);  spl[r]  += __shfl_xor(spl[r], 2);
      spl[r]  += __shfl_xor(spl[r], 4);  spl[r]  += __shfl_xor(spl[r], 8);
      spcl[r] += __shfl_xor(spcl[r], 1); spcl[r] += __shfl_xor(spcl[r], 2);
      spcl[r] += __shfl_xor(spcl[r], 4); spcl[r] += __shfl_xor(spcl[r], 8);
      sp_r[r]  = sp_r[r]  * alpha[r] + spl[r];
      spc_r[r] = spc_r[r] * alpha[r] + spcl[r];
    }
    // rescale O accumulators
    #pragma unroll
    for (int dn = 0; dn < 8; dn++)
      #pragma unroll
      for (int r = 0; r < 4; r++)
        oacc[dn][r] *= alpha[r];

    __syncthreads();   // make P LDS writes visible (cross-lane within wave)

    // O += P @ V : A-frags from Pw, B-frags from Vtsh
    short8v pa[2];
    #pragma unroll
    for (int kc = 0; kc < 2; kc++)
      pa[kc] = *(const short8v*)&Pw[(l15 * 9 + kc * 4 + quad) * 8];
    #pragma unroll
    for (int dn = 0; dn < 8; dn++) {
      #pragma unroll
      for (int kc = 0; kc < 2; kc++) {
        short8v vf = *(const short8v*)&Vtsh[((dn * 16 + l15) * 9 + kc * 4 + quad) * 8];
        oacc[dn] = __builtin_amdgcn_mfma_f32_16x16x32_bf16(pa[kc], vf, oacc[dn], 0, 0, 0);
      }
    }
  }

  // epilogue: normalize and store fp32
  float inv[4];
  #pragma unroll
  for (int r = 0; r < 4; r++) inv[r] = 1.0f / (spc_r[r] + 1e-8f * sp_r[r]);
  #pragma unroll
  for (int dn = 0; dn < 8; dn++)
    #pragma unroll
    for (int r = 0; r < 4; r++)
      Oc[((size_t)(b * NN + q0w + quad * 4 + r)) * HH + dn * 16 + l15] = oacc[dn][r] * inv[r];
}

// ---------------------------------------------------------------------------
// GCN gather
// ---------------------------------------------------------------------------
__global__ __launch_bounds__(256) void k_gather(
    const float* __restrict__ hW, const float* __restrict__ bias,
    const int* __restrict__ roff, const int* __restrict__ col,
    const float* __restrict__ wn, const float* __restrict__ dinv,
    float* __restrict__ out)
{
  const int t = threadIdx.x;
  const size_t idx = (size_t)blockIdx.x * 2 + (t >> 7);
  const int c = t & 127;
  const int b = (int)(idx >> 9);
  const int i = (int)(idx & 511);
  const float* base = hW + (size_t)b * NN * HH;
  float di = dinv[i];
  float acc = base[(size_t)i * HH + c] * di * di;
  int p0 = roff[i], p1 = roff[i + 1];
  for (int p = p0; p < p1; p++)
    acc = fmaf(base[(size_t)col[p] * HH + c], wn[p], acc);
  acc += bias[c];
  out[idx * HH + c] = fmaxf(acc, 0.f);
}

// ---------------------------------------------------------------------------
// LayerNorm over H=128 + affine
// ---------------------------------------------------------------------------
__global__ __launch_bounds__(256) void k_ln(
    const float* __restrict__ X, const float* __restrict__ g,
    const float* __restrict__ bt, float* __restrict__ out)
{
  const int t = threadIdx.x;
  const size_t row = (size_t)blockIdx.x * 2 + (t >> 7);
  const int c = t & 127;
  const int hr = t >> 7;
  __shared__ float red[2][128];
  float v = X[row * HH + c];
  red[hr][c] = v; __syncthreads();
  for (int s = 64; s > 0; s >>= 1) { if (c < s) red[hr][c] += red[hr][c + s]; __syncthreads(); }
  float mu = red[hr][0] * (1.0f / 128.0f);
  __syncthreads();
  float d = v - mu;
  red[hr][c] = d * d; __syncthreads();
  for (int s = 64; s > 0; s >>= 1) { if (c < s) red[hr][c] += red[hr][c + s]; __syncthreads(); }
  float var = red[hr][0] * (1.0f / 128.0f);
  float inv = rsqrtf(var + 1e-5f);
  out[row * HH + c] = d * inv * g[c] + bt[c];
}

// ---------------------------------------------------------------------------
// Buffer schedule (3 x 64MB fp32 ws slots + aux; bf16 Q/K overlay T2,
// bf16 Vt overlays d_out's out-region which is scratch until final LN):
//  h->T0 ; hW1->T1 ; g1->T2 ; hW2->T1 ; g2->T2 ; comb=g2@Wf_bot+bf->T1 ;
//  Qbf->T2[0:] ; Kbf->T2[half:] ; Vtbf->outp ; attn->T0 ;
//  comb+=hc@Wf_top (T1) ; LN(T1)->outp
// ---------------------------------------------------------------------------
extern "C" void kernel_launch(void* const* d_in, const int* in_sizes, int n_in,
                              void* d_out, int out_size, void* d_ws, size_t ws_size,
                              hipStream_t stream)
{
  const float* x     = (const float*)d_in[0];
  const int*   ei    = (const int*)d_in[1];
  const float* adj   = (const float*)d_in[2];
  const float* dmask = (const float*)d_in[3];
  const float* clog  = (const float*)d_in[4];
  const float* W_in  = (const float*)d_in[5];
  const float* b_in  = (const float*)d_in[6];
  const float* Wq    = (const float*)d_in[7];
  const float* bq    = (const float*)d_in[8];
  const float* Wk    = (const float*)d_in[9];
  const float* bk    = (const float*)d_in[10];
  const float* Wv    = (const float*)d_in[11];
  const float* bv    = (const float*)d_in[12];
  const float* gcnW  = (const float*)d_in[13];
  const float* gcnB  = (const float*)d_in[14];
  const float* Wf    = (const float*)d_in[15];
  const float* bf    = (const float*)d_in[16];
  const float* lng   = (const float*)d_in[17];
  const float* lnb   = (const float*)d_in[18];

  float* outp = (float*)d_out;
  float* Cmat = outp + OUT0;

  float* F = (float*)d_ws;
  const size_t BUF = (size_t)OUT0;
  float* T0   = F;
  float* T1   = F + BUF;
  float* T2   = F + 2 * BUF;
  float* dinv = F + 3 * BUF;
  float* wn   = dinv + 512;
  int*   roff = (int*)(wn + NE);
  int*   col  = roff + 516;

  unsigned short* Qbf  = (unsigned short*)T2;
  unsigned short* Kbf  = Qbf + (size_t)MROWS * HH;
  unsigned short* Vtbf = (unsigned short*)outp;   // out region is scratch until LN

  const int ntiles = MROWS / 32;   // 4096

  k_causalC<<<512, 256, 0, stream>>>(clog, adj, dmask, Cmat);
  k_graph<<<1, 512, 0, stream>>>(ei, dinv, roff, col, wn);
  // h = relu(x @ W_in + b_in) -> T0
  k_gemm<64, true, false, 0><<<1024, 256, 0, stream>>>(x, W_in, b_in, T0, ntiles);
  // GCN layer 0
  k_gemm<128, false, false, 0><<<1024, 256, 0, stream>>>(T0, gcnW, nullptr, T1, ntiles);
  k_gather<<<MROWS / 2, 256, 0, stream>>>(T1, gcnB, roff, col, wn, dinv, T2);
  // GCN layer 1
  k_gemm<128, false, false, 0><<<1024, 256, 0, stream>>>(T2, gcnW + HH * HH, nullptr, T1, ntiles);
  k_gather<<<MROWS / 2, 256, 0, stream>>>(T1, gcnB + HH, roff, col, wn, dinv, T2);
  // comb = g2 @ Wf_bot + bf -> T1
  k_gemm<128, false, false, 0><<<1024, 256, 0, stream>>>(T2, Wf + HH * HH, bf, T1, ntiles);
  // Q,K (bf16 row-major into T2), V (bf16 transposed into outp scratch)
  k_gemm<128, false, false, 1><<<1024, 256, 0, stream>>>(T0, Wq, bq, (float*)Qbf, ntiles);
  k_gemm<128, false, false, 1><<<1024, 256, 0, stream>>>(T0, Wk, bk, (float*)Kbf, ntiles);
  k_gemm<128, false, false, 2><<<1024, 256, 0, stream>>>(T0, Wv, bv, (float*)Vtbf, ntiles);
  // MFMA flash attention -> hc (T0, h now dead)
  k_attn_mfma<<<BB * 8, 256, 0, stream>>>(Qbf, Kbf, Vtbf, Cmat, T0);
  // comb += hc @ Wf_top
  k_gemm<128, false, true, 0><<<1024, 256, 0, stream>>>(T0, Wf, nullptr, T1, ntiles);
  // layernorm -> out
  k_ln<<<MROWS / 2, 256, 0, stream>>>(T1, lng, lnb, outp);
}

// Round 4
// 631.610 us; speedup vs baseline: 3.1808x; 2.1124x over previous
//
#include <hip/hip_runtime.h>
#include <hip/hip_bf16.h>
#include <math.h>

#define NN 512
#define HH 128
#define INDIM 64
#define BB 256
#define NE 4096               // directed edge count (2*E_UND)
#define MROWS (BB*NN)         // 131072
#define OUT0 (BB*NN*HH)       // 16777216 floats, start of C in d_out

typedef __attribute__((ext_vector_type(8))) short short8v;
typedef __attribute__((ext_vector_type(4))) float float4v;

__device__ __forceinline__ unsigned short f2bf(float f) {
  unsigned u = __float_as_uint(f);
  unsigned r = (u + 0x7fffu + ((u >> 16) & 1u)) >> 16;   // RNE
  return (unsigned short)r;
}

// ---------------------------------------------------------------------------
// C = softmax(logits,-1) * adj * dir; C /= max(rowsum, 1e-8)
// ---------------------------------------------------------------------------
__global__ __launch_bounds__(256) void k_causalC(
    const float* __restrict__ logits, const float* __restrict__ adj,
    const float* __restrict__ dir, float* __restrict__ Cout)
{
  const int row = blockIdx.x;
  const int t = threadIdx.x;
  __shared__ float red[256];
  const float* lrow = logits + (size_t)row * NN;
  float v0 = lrow[t], v1 = lrow[t + 256];
  float mx = fmaxf(v0, v1);
  red[t] = mx; __syncthreads();
  for (int s = 128; s > 0; s >>= 1) { if (t < s) red[t] = fmaxf(red[t], red[t + s]); __syncthreads(); }
  mx = red[0]; __syncthreads();
  float e0 = __expf(v0 - mx), e1 = __expf(v1 - mx);
  red[t] = e0 + e1; __syncthreads();
  for (int s = 128; s > 0; s >>= 1) { if (t < s) red[t] += red[t + s]; __syncthreads(); }
  float sumE = red[0]; __syncthreads();
  float m0 = adj[(size_t)row * NN + t] * dir[(size_t)row * NN + t];
  float m1 = adj[(size_t)row * NN + t + 256] * dir[(size_t)row * NN + t + 256];
  float me0 = e0 * m0, me1 = e1 * m1;
  red[t] = me0 + me1; __syncthreads();
  for (int s = 128; s > 0; s >>= 1) { if (t < s) red[t] += red[t + s]; __syncthreads(); }
  float sumME = red[0];
  float sm = sumME / sumE;
  float denom = fmaxf(sm, 1e-8f) * sumE;
  Cout[(size_t)row * NN + t]       = me0 / denom;
  Cout[(size_t)row * NN + t + 256] = me1 / denom;
}

// ---------------------------------------------------------------------------
// Dense normalized adjacency Ahat (fp32, 512x512): Ahat[d][s] += dinv_s*dinv_d
// per directed edge (duplicates accumulate, matching scatter-add), diagonal
// += dinv_i^2 (self loop). deg = in-degree incl. duplicates + 1.
// ---------------------------------------------------------------------------
__global__ __launch_bounds__(512) void k_ahat(const int* __restrict__ ei,
                                              float* __restrict__ Ahat)
{
  __shared__ int scnt[512];
  __shared__ float sdinv[512];
  const int t = threadIdx.x;
  float4 z = {0.f, 0.f, 0.f, 0.f};
  for (int i = t; i < 65536; i += 512) ((float4*)Ahat)[i] = z;
  scnt[t] = 0;
  __syncthreads();
  const int* src = ei;
  const int* dst = ei + NE;
  for (int e = t; e < NE; e += 512) atomicAdd(&scnt[dst[e]], 1);
  __syncthreads();
  sdinv[t] = rsqrtf((float)(scnt[t] + 1));
  __threadfence();          // zero-stores visible before global atomics
  __syncthreads();
  for (int e = t; e < NE; e += 512) {
    int s = src[e], d = dst[e];
    atomicAdd(&Ahat[(size_t)d * 512 + s], sdinv[s] * sdinv[d]);
  }
  float di = sdinv[t];
  atomicAdd(&Ahat[(size_t)t * 512 + t], di * di);
}

// ---------------------------------------------------------------------------
// fp32 -> bf16 convert (straight), vectorized x4
// ---------------------------------------------------------------------------
__global__ void k_f2b(const float* __restrict__ s, unsigned short* __restrict__ d, int n4)
{
  int i = blockIdx.x * blockDim.x + threadIdx.x;
  int stride = gridDim.x * blockDim.x;
  for (; i < n4; i += stride) {
    float4 v = ((const float4*)s)[i];
    uint2 pk;
    pk.x = (unsigned)f2bf(v.x) | ((unsigned)f2bf(v.y) << 16);
    pk.y = (unsigned)f2bf(v.z) | ((unsigned)f2bf(v.w) << 16);
    ((uint2*)d)[i] = pk;
  }
}

// ---------------------------------------------------------------------------
// Weight transpose+convert: src fp32 (K x 128) -> dst bf16 (128 x K).
// One block per job. Jobs: W_in(64), Wq,Wk,Wv(128), gcnW0,gcnW1(128), Wf(256).
// ---------------------------------------------------------------------------
__global__ __launch_bounds__(256) void k_wt(
    const float* s0, const float* s1, const float* s2, const float* s3,
    const float* s4, const float* s5, const float* s6,
    unsigned short* d0, unsigned short* d1, unsigned short* d2, unsigned short* d3,
    unsigned short* d4, unsigned short* d5, unsigned short* d6)
{
  const float* srcs[7] = {s0, s1, s2, s3, s4, s5, s6};
  unsigned short* dsts[7] = {d0, d1, d2, d3, d4, d5, d6};
  const int Ks[7] = {64, 128, 128, 128, 128, 128, 256};
  int j = blockIdx.x;
  const float* s = srcs[j];
  unsigned short* d = dsts[j];
  int K = Ks[j];
  for (int idx = threadIdx.x; idx < K * 128; idx += 256) {
    int k = idx >> 7, n = idx & 127;
    d[n * K + k] = f2bf(s[idx]);
  }
}

// ---------------------------------------------------------------------------
// bf16 MFMA GEMM: Out(M=131072, N=128) = A(M,KD) @ W(KD,128) [+bias][relu]
//  A: bf16 row-major.  Wt: bf16 W-transposed (128 x KD row-major).
//  BATCHW: A row index = global_row & 511 (shared Ahat), Wt += batch*128*KD
//          (per-batch transposed hW) — implements per-batch Ahat @ hW.
//  OMODE 0: bf16 row-major out, runtime stride OS (128 or 256, ptr pre-offset)
//  OMODE 1: bf16 transposed-per-batch out: Out[(b*128+c)*512 + node]
//  OMODE 2: fp32 out stride 128 with fused LayerNorm (lng/lnb)
// Block: 64 rows x 128 cols, 4 waves (wave = 16 rows, all cols, 8 acc tiles).
// LDS strides padded +8 shorts -> <=2-way bank aliasing (free).
// ---------------------------------------------------------------------------
template<int KD, bool RELU, bool BATCHW, int OMODE>
__global__ __launch_bounds__(256) void k_bgemm(
    const unsigned short* __restrict__ A, const unsigned short* __restrict__ Wt,
    const float* __restrict__ bias, void* __restrict__ Out, int OS,
    const float* __restrict__ lng, const float* __restrict__ lnb)
{
  constexpr int KCH = (KD < 128) ? KD : 128;
  constexpr int STR = KCH + 8;
  __shared__ short lds[192 * STR];          // A: 64*STR, Wt: 128*STR
  short* As = lds;
  short* Ws = lds + 64 * STR;
  const int t = threadIdx.x;
  const int wave = t >> 6, lane = t & 63;
  const int l15 = lane & 15, quad = lane >> 4;

  float bcol[8];
  #pragma unroll
  for (int nt = 0; nt < 8; nt++) bcol[nt] = bias ? bias[nt * 16 + l15] : 0.f;
  float gcol[8], bbcol[8];
  if (OMODE == 2) {
    #pragma unroll
    for (int nt = 0; nt < 8; nt++) { gcol[nt] = lng[nt * 16 + l15]; bbcol[nt] = lnb[nt * 16 + l15]; }
  }

  for (int tile = blockIdx.x; tile < MROWS / 64; tile += gridDim.x) {
    const int rowbase = tile * 64;
    const int b = rowbase >> 9;
    const unsigned short* Wb = BATCHW ? (Wt + (size_t)b * 128 * KD) : Wt;
    float4v acc[8];
    #pragma unroll
    for (int nt = 0; nt < 8; nt++) acc[nt] = (float4v){0.f, 0.f, 0.f, 0.f};

    for (int kc = 0; kc < KD; kc += KCH) {
      __syncthreads();
      for (int i = t; i < 64 * (KCH / 8); i += 256) {
        int r = i / (KCH / 8), seg = i % (KCH / 8);
        int arow = BATCHW ? ((rowbase & 511) + r) : (rowbase + r);
        *(short8v*)&As[r * STR + seg * 8] =
            *(const short8v*)&A[(size_t)arow * KD + kc + seg * 8];
      }
      for (int i = t; i < 128 * (KCH / 8); i += 256) {
        int n = i / (KCH / 8), seg = i % (KCH / 8);
        *(short8v*)&Ws[n * STR + seg * 8] =
            *(const short8v*)&Wb[(size_t)n * KD + kc + seg * 8];
      }
      __syncthreads();
      #pragma unroll
      for (int k32 = 0; k32 < KCH / 32; k32++) {
        short8v af = *(const short8v*)&As[(wave * 16 + l15) * STR + k32 * 32 + quad * 8];
        #pragma unroll
        for (int nt = 0; nt < 8; nt++) {
          short8v wf = *(const short8v*)&Ws[(nt * 16 + l15) * STR + k32 * 32 + quad * 8];
          acc[nt] = __builtin_amdgcn_mfma_f32_16x16x32_bf16(af, wf, acc[nt], 0, 0, 0);
        }
      }
    }

    __syncthreads();                         // done with As/Ws; reuse for repack
    if (OMODE == 0) {
      short* rep = lds + wave * 2048;
      #pragma unroll
      for (int nt = 0; nt < 8; nt++)
        #pragma unroll
        for (int r = 0; r < 4; r++) {
          float v = acc[nt][r] + bcol[nt];
          if (RELU) v = fmaxf(v, 0.f);
          rep[(quad * 4 + r) * 128 + nt * 16 + l15] = (short)f2bf(v);
        }
      __syncthreads();
      unsigned short* Ob = (unsigned short*)Out;
      #pragma unroll
      for (int p = 0; p < 4; p++) {
        int row16 = (lane >> 4) + p * 4, seg = lane & 15;
        short8v vv = *(const short8v*)&rep[row16 * 128 + seg * 8];
        *(short8v*)&Ob[(size_t)(rowbase + wave * 16 + row16) * OS + seg * 8] = vv;
      }
    } else if (OMODE == 1) {
      short* rep = lds + wave * 2048;        // [c:128][node:16]
      #pragma unroll
      for (int nt = 0; nt < 8; nt++)
        #pragma unroll
        for (int r = 0; r < 4; r++) {
          float v = acc[nt][r] + bcol[nt];
          if (RELU) v = fmaxf(v, 0.f);
          rep[(nt * 16 + l15) * 16 + quad * 4 + r] = (short)f2bf(v);
        }
      __syncthreads();
      unsigned short* Ob = (unsigned short*)Out;
      int node0 = (rowbase & 511) + wave * 16;
      #pragma unroll
      for (int p = 0; p < 4; p++) {
        int idx = p * 64 + lane, c = idx >> 1, half = idx & 1;
        short8v vv = *(const short8v*)&rep[c * 16 + half * 8];
        *(short8v*)&Ob[((size_t)(b * 128 + c)) * 512 + node0 + half * 8] = vv;
      }
    } else {
      float* repw = (float*)lds + wave * 2048;
      float vv[8][4];
      float s[4] = {0, 0, 0, 0}, ss[4] = {0, 0, 0, 0};
      #pragma unroll
      for (int nt = 0; nt < 8; nt++)
        #pragma unroll
        for (int r = 0; r < 4; r++) {
          float v = acc[nt][r] + bcol[nt];
          vv[nt][r] = v;
          s[r] += v; ss[r] += v * v;
        }
      #pragma unroll
      for (int r = 0; r < 4; r++) {
        s[r] += __shfl_xor(s[r], 1);  s[r] += __shfl_xor(s[r], 2);
        s[r] += __shfl_xor(s[r], 4);  s[r] += __shfl_xor(s[r], 8);
        ss[r] += __shfl_xor(ss[r], 1); ss[r] += __shfl_xor(ss[r], 2);
        ss[r] += __shfl_xor(ss[r], 4); ss[r] += __shfl_xor(ss[r], 8);
      }
      #pragma unroll
      for (int r = 0; r < 4; r++) {
        float mu = s[r] * (1.0f / 128.0f);
        float var = ss[r] * (1.0f / 128.0f) - mu * mu;
        float inv = rsqrtf(var + 1e-5f);
        #pragma unroll
        for (int nt = 0; nt < 8; nt++)
          repw[(quad * 4 + r) * 128 + nt * 16 + l15] =
              (vv[nt][r] - mu) * inv * gcol[nt] + bbcol[nt];
      }
      __syncthreads();
      float* Of = (float*)Out;
      #pragma unroll
      for (int p = 0; p < 8; p++) {
        int row16 = (lane >> 5) + p * 2, seg = lane & 31;
        float4 o = *(const float4*)&repw[row16 * 128 + seg * 4];
        *(float4*)&Of[(size_t)(rowbase + wave * 16 + row16) * 128 + seg * 4] = o;
      }
    }
  }
}

// ---------------------------------------------------------------------------
// MFMA flash attention (bf16), out = sum p*C*V / (sum pC + 1e-8 sum p).
// Output bf16, row stride 256 (interleaved concat buffer, offset 0).
// ---------------------------------------------------------------------------
__global__ __launch_bounds__(256) void k_attn_mfma(
    const unsigned short* __restrict__ Qbf, const unsigned short* __restrict__ Kbf,
    const unsigned short* __restrict__ Vtbf, const float* __restrict__ C,
    unsigned short* __restrict__ Ocb)
{
  const int b = blockIdx.x >> 3;
  const int qblk = blockIdx.x & 7;
  const int t = threadIdx.x;
  const int wave = t >> 6, lane = t & 63;
  const int l15 = lane & 15, quad = lane >> 4;
  const int q0w = qblk * 64 + wave * 16;

  __shared__ short Ksh[64 * 17 * 8];
  __shared__ short Vtsh[128 * 9 * 8];
  __shared__ short Psh[4 * 16 * 9 * 8];
  short* Pw = Psh + wave * (16 * 9 * 8);

  short8v qf[4];
  #pragma unroll
  for (int dc = 0; dc < 4; dc++)
    qf[dc] = *(const short8v*)&Qbf[((size_t)(b * NN + q0w + l15)) * HH + dc * 32 + quad * 8];

  float m_r[4], sp_r[4], spc_r[4];
  #pragma unroll
  for (int r = 0; r < 4; r++) { m_r[r] = -INFINITY; sp_r[r] = 0.f; spc_r[r] = 0.f; }
  float4v oacc[8];
  #pragma unroll
  for (int dn = 0; dn < 8; dn++) oacc[dn] = (float4v){0.f, 0.f, 0.f, 0.f};

  const float scale = 0.088388347648318447f;

  for (int kt = 0; kt < 8; kt++) {
    const int k0 = kt * 64;
    __syncthreads();
    for (int i = t; i < 64 * 16; i += 256) {
      int row = i >> 4, seg = i & 15;
      *(short8v*)&Ksh[(row * 17 + seg) * 8] =
          *(const short8v*)&Kbf[((size_t)(b * NN + k0 + row)) * HH + seg * 8];
    }
    for (int i = t; i < 128 * 8; i += 256) {
      int row = i >> 3, seg = i & 7;
      *(short8v*)&Vtsh[(row * 9 + seg) * 8] =
          *(const short8v*)&Vtbf[((size_t)(b * HH + row)) * NN + k0 + seg * 8];
    }
    __syncthreads();

    float cv[4][4];
    #pragma unroll
    for (int n = 0; n < 4; n++)
      #pragma unroll
      for (int r = 0; r < 4; r++)
        cv[n][r] = C[(size_t)(q0w + quad * 4 + r) * NN + k0 + n * 16 + l15];

    float4v sacc[4];
    #pragma unroll
    for (int n = 0; n < 4; n++) {
      sacc[n] = (float4v){0.f, 0.f, 0.f, 0.f};
      #pragma unroll
      for (int dc = 0; dc < 4; dc++) {
        short8v kf = *(const short8v*)&Ksh[((n * 16 + l15) * 17 + dc * 4 + quad) * 8];
        sacc[n] = __builtin_amdgcn_mfma_f32_16x16x32_bf16(qf[dc], kf, sacc[n], 0, 0, 0);
      }
    }

    float sv[4][4], lm[4];
    #pragma unroll
    for (int r = 0; r < 4; r++) lm[r] = -INFINITY;
    #pragma unroll
    for (int n = 0; n < 4; n++)
      #pragma unroll
      for (int r = 0; r < 4; r++) {
        float sx = sacc[n][r] * scale;
        sv[n][r] = sx;
        lm[r] = fmaxf(lm[r], sx);
      }
    #pragma unroll
    for (int r = 0; r < 4; r++) {
      lm[r] = fmaxf(lm[r], __shfl_xor(lm[r], 1));
      lm[r] = fmaxf(lm[r], __shfl_xor(lm[r], 2));
      lm[r] = fmaxf(lm[r], __shfl_xor(lm[r], 4));
      lm[r] = fmaxf(lm[r], __shfl_xor(lm[r], 8));
    }
    float alpha[4];
    #pragma unroll
    for (int r = 0; r < 4; r++) {
      float mnew = fmaxf(m_r[r], lm[r]);
      alpha[r] = __expf(m_r[r] - mnew);
      m_r[r] = mnew;
    }
    float spl[4] = {0.f, 0.f, 0.f, 0.f}, spcl[4] = {0.f, 0.f, 0.f, 0.f};
    #pragma unroll
    for (int n = 0; n < 4; n++)
      #pragma unroll
      for (int r = 0; r < 4; r++) {
        float p = __expf(sv[n][r] - m_r[r]);
        float pcv = p * cv[n][r];
        spl[r] += p; spcl[r] += pcv;
        Pw[(quad * 4 + r) * 72 + n * 16 + l15] = (short)f2bf(pcv);
      }
    #pragma unroll
    for (int r = 0; r < 4; r++) {
      spl[r]  += __shfl_xor(spl[r], 1);  spl[r]  += __shfl_xor(spl[r], 2);
      spl[r]  += __shfl_xor(spl[r], 4);  spl[r]  += __shfl_xor(spl[r], 8);
      spcl[r] += __shfl_xor(spcl[r], 1); spcl[r] += __shfl_xor(spcl[r], 2);
      spcl[r] += __shfl_xor(spcl[r], 4); spcl[r] += __shfl_xor(spcl[r], 8);
      sp_r[r]  = sp_r[r]  * alpha[r] + spl[r];
      spc_r[r] = spc_r[r] * alpha[r] + spcl[r];
    }
    #pragma unroll
    for (int dn = 0; dn < 8; dn++)
      #pragma unroll
      for (int r = 0; r < 4; r++)
        oacc[dn][r] *= alpha[r];

    __syncthreads();

    short8v pa[2];
    #pragma unroll
    for (int kc = 0; kc < 2; kc++)
      pa[kc] = *(const short8v*)&Pw[(l15 * 9 + kc * 4 + quad) * 8];
    #pragma unroll
    for (int dn = 0; dn < 8; dn++) {
      #pragma unroll
      for (int kc = 0; kc < 2; kc++) {
        short8v vf = *(const short8v*)&Vtsh[((dn * 16 + l15) * 9 + kc * 4 + quad) * 8];
        oacc[dn] = __builtin_amdgcn_mfma_f32_16x16x32_bf16(pa[kc], vf, oacc[dn], 0, 0, 0);
      }
    }
  }

  float inv[4];
  #pragma unroll
  for (int r = 0; r < 4; r++) inv[r] = 1.0f / (spc_r[r] + 1e-8f * sp_r[r]);
  #pragma unroll
  for (int dn = 0; dn < 8; dn++)
    #pragma unroll
    for (int r = 0; r < 4; r++)
      Ocb[((size_t)(b * NN + q0w + quad * 4 + r)) * 256 + dn * 16 + l15] =
          f2bf(oacc[dn][r] * inv[r]);
}

// ---------------------------------------------------------------------------
// ws layout (bytes):
//   A0 @ 0        (33.5MB): xbf -> g1 -> Kbf
//   B0 @ 32MB*1.. : h bf16
//   C0            : hWt (per-batch transposed) -> Qbf
//   D0            : comb bf16 interleaved, stride 256 (attn @0, g2 @128)
//   AUX           : Ahat fp32 (1MB) | Ahat bf16 (0.5MB) | weights bf16 (240KB)
// Vt bf16 lives in d_out's out-region (scratch until final fused-LN GEMM).
// ---------------------------------------------------------------------------
extern "C" void kernel_launch(void* const* d_in, const int* in_sizes, int n_in,
                              void* d_out, int out_size, void* d_ws, size_t ws_size,
                              hipStream_t stream)
{
  const float* x     = (const float*)d_in[0];
  const int*   ei    = (const int*)d_in[1];
  const float* adj   = (const float*)d_in[2];
  const float* dmask = (const float*)d_in[3];
  const float* clog  = (const float*)d_in[4];
  const float* W_in  = (const float*)d_in[5];
  const float* b_in  = (const float*)d_in[6];
  const float* Wq    = (const float*)d_in[7];
  const float* bq    = (const float*)d_in[8];
  const float* Wk    = (const float*)d_in[9];
  const float* bk    = (const float*)d_in[10];
  const float* Wv    = (const float*)d_in[11];
  const float* bv    = (const float*)d_in[12];
  const float* gcnW  = (const float*)d_in[13];
  const float* gcnB  = (const float*)d_in[14];
  const float* Wf    = (const float*)d_in[15];
  const float* bf    = (const float*)d_in[16];
  const float* lng   = (const float*)d_in[17];
  const float* lnb   = (const float*)d_in[18];

  float* outp = (float*)d_out;
  float* Cmat = outp + OUT0;

  char* W = (char*)d_ws;
  const size_t SLOT = (size_t)MROWS * 128 * 2;       // 33,554,432 B
  unsigned short* A0 = (unsigned short*)(W);
  unsigned short* B0 = (unsigned short*)(W + SLOT);
  unsigned short* C0 = (unsigned short*)(W + 2 * SLOT);
  unsigned short* D0 = (unsigned short*)(W + 3 * SLOT);   // 2*SLOT bytes
  char* AUX = W + 5 * SLOT;
  float*          AhatF = (float*)AUX;                    // 512*512 fp32
  unsigned short* AhatB = (unsigned short*)(AUX + 512 * 512 * 4);
  unsigned short* WB    = AhatB + 512 * 512;              // weights bf16
  unsigned short* W_int = WB;            // 128x64
  unsigned short* Wqt   = WB + 8192;     // 128x128
  unsigned short* Wkt   = Wqt + 16384;
  unsigned short* Wvt   = Wkt + 16384;
  unsigned short* G0t   = Wvt + 16384;
  unsigned short* G1t   = G0t + 16384;
  unsigned short* Wft   = G1t + 16384;   // 128x256

  unsigned short* xbf  = A0;
  unsigned short* Vtbf = (unsigned short*)outp;      // scratch until fuse GEMM

  // --- prep ---
  k_causalC<<<512, 256, 0, stream>>>(clog, adj, dmask, Cmat);
  k_ahat<<<1, 512, 0, stream>>>(ei, AhatF);
  k_f2b<<<256, 256, 0, stream>>>(AhatF, AhatB, 512 * 512 / 4);
  k_wt<<<7, 256, 0, stream>>>(W_in, Wq, Wk, Wv, gcnW, gcnW + HH * HH, Wf,
                              W_int, Wqt, Wkt, Wvt, G0t, G1t, Wft);
  k_f2b<<<2048, 256, 0, stream>>>(x, xbf, MROWS * INDIM / 4);

  // --- h = relu(x @ W_in + b_in) -> B0 ---
  k_bgemm<64, true, false, 0><<<2048, 256, 0, stream>>>(
      xbf, W_int, b_in, B0, 128, nullptr, nullptr);
  // --- GCN layer 0: hWt -> C0 ; g1 = relu(Ahat@hW + b0) -> A0 ---
  k_bgemm<128, false, false, 1><<<2048, 256, 0, stream>>>(
      B0, G0t, nullptr, C0, 0, nullptr, nullptr);
  k_bgemm<512, true, true, 0><<<2048, 256, 0, stream>>>(
      AhatB, C0, gcnB, A0, 128, nullptr, nullptr);
  // --- GCN layer 1: hWt -> C0 ; g2 -> D0 col 128 (stride 256) ---
  k_bgemm<128, false, false, 1><<<2048, 256, 0, stream>>>(
      A0, G1t, nullptr, C0, 0, nullptr, nullptr);
  k_bgemm<512, true, true, 0><<<2048, 256, 0, stream>>>(
      AhatB, C0, gcnB + HH, D0 + 128, 256, nullptr, nullptr);
  // --- Q -> C0, K -> A0, Vt -> outp ---
  k_bgemm<128, false, false, 0><<<2048, 256, 0, stream>>>(
      B0, Wqt, bq, C0, 128, nullptr, nullptr);
  k_bgemm<128, false, false, 0><<<2048, 256, 0, stream>>>(
      B0, Wkt, bk, A0, 128, nullptr, nullptr);
  k_bgemm<128, false, false, 1><<<2048, 256, 0, stream>>>(
      B0, Wvt, bv, Vtbf, 0, nullptr, nullptr);
  // --- attention -> D0 col 0 (stride 256) ---
  k_attn_mfma<<<BB * 8, 256, 0, stream>>>(C0, A0, Vtbf, Cmat, D0);
  // --- fuse + fused LayerNorm -> outp ---
  k_bgemm<256, false, false, 2><<<2048, 256, 0, stream>>>(
      D0, Wft, bf, outp, 128, lng, lnb);
}

// Round 6
// 627.577 us; speedup vs baseline: 3.2012x; 1.0064x over previous
//
#include <hip/hip_runtime.h>
#include <hip/hip_bf16.h>
#include <math.h>

#define NN 512
#define HH 128
#define INDIM 64
#define BB 256
#define NE 4096               // directed edge count (2*E_UND)
#define MROWS (BB*NN)         // 131072
#define OUT0 (BB*NN*HH)       // 16777216 floats, start of C in d_out

typedef __attribute__((ext_vector_type(8))) short short8v;
typedef __attribute__((ext_vector_type(4))) float float4v;

__device__ __forceinline__ unsigned short f2bf(float f) {
  unsigned u = __float_as_uint(f);
  unsigned r = (u + 0x7fffu + ((u >> 16) & 1u)) >> 16;   // RNE
  return (unsigned short)r;
}
__device__ __forceinline__ float bf2f(unsigned short b) {
  return __uint_as_float(((unsigned)b) << 16);
}

// ---------------------------------------------------------------------------
// C = softmax(logits,-1) * adj * dir; C /= max(rowsum, 1e-8)
// Writes fp32 (output) + bf16 copy for the attention kernel.
// ---------------------------------------------------------------------------
__global__ __launch_bounds__(256) void k_causalC(
    const float* __restrict__ logits, const float* __restrict__ adj,
    const float* __restrict__ dir, float* __restrict__ Cout,
    unsigned short* __restrict__ CB)
{
  const int row = blockIdx.x;
  const int t = threadIdx.x;
  __shared__ float red[256];
  const float* lrow = logits + (size_t)row * NN;
  float v0 = lrow[t], v1 = lrow[t + 256];
  float mx = fmaxf(v0, v1);
  red[t] = mx; __syncthreads();
  for (int s = 128; s > 0; s >>= 1) { if (t < s) red[t] = fmaxf(red[t], red[t + s]); __syncthreads(); }
  mx = red[0]; __syncthreads();
  float e0 = __expf(v0 - mx), e1 = __expf(v1 - mx);
  red[t] = e0 + e1; __syncthreads();
  for (int s = 128; s > 0; s >>= 1) { if (t < s) red[t] += red[t + s]; __syncthreads(); }
  float sumE = red[0]; __syncthreads();
  float m0 = adj[(size_t)row * NN + t] * dir[(size_t)row * NN + t];
  float m1 = adj[(size_t)row * NN + t + 256] * dir[(size_t)row * NN + t + 256];
  float me0 = e0 * m0, me1 = e1 * m1;
  red[t] = me0 + me1; __syncthreads();
  for (int s = 128; s > 0; s >>= 1) { if (t < s) red[t] += red[t + s]; __syncthreads(); }
  float sumME = red[0];
  float sm = sumME / sumE;
  float denom = fmaxf(sm, 1e-8f) * sumE;
  float c0 = me0 / denom, c1 = me1 / denom;
  Cout[(size_t)row * NN + t]       = c0;
  Cout[(size_t)row * NN + t + 256] = c1;
  CB[(size_t)row * NN + t]         = f2bf(c0);
  CB[(size_t)row * NN + t + 256]   = f2bf(c1);
}

// ---------------------------------------------------------------------------
// Dense normalized adjacency Ahat (fp32, 512x512): Ahat[d][s] += dinv_s*dinv_d
// per directed edge (duplicates accumulate), diag += dinv^2.  (proven r4 path)
// ---------------------------------------------------------------------------
__global__ __launch_bounds__(512) void k_ahat(const int* __restrict__ ei,
                                              float* __restrict__ Ahat)
{
  __shared__ int scnt[512];
  __shared__ float sdinv[512];
  const int t = threadIdx.x;
  float4 z = {0.f, 0.f, 0.f, 0.f};
  for (int i = t; i < 65536; i += 512) ((float4*)Ahat)[i] = z;
  scnt[t] = 0;
  __syncthreads();
  const int* src = ei;
  const int* dst = ei + NE;
  for (int e = t; e < NE; e += 512) atomicAdd(&scnt[dst[e]], 1);
  __syncthreads();
  sdinv[t] = rsqrtf((float)(scnt[t] + 1));
  __threadfence();          // zero-stores visible before global atomics
  __syncthreads();
  for (int e = t; e < NE; e += 512) {
    int s = src[e], d = dst[e];
    atomicAdd(&Ahat[(size_t)d * 512 + s], sdinv[s] * sdinv[d]);
  }
  float di = sdinv[t];
  atomicAdd(&Ahat[(size_t)t * 512 + t], di * di);
}

// ---------------------------------------------------------------------------
// fp32 -> bf16 convert, vectorized x4
// ---------------------------------------------------------------------------
__global__ void k_f2b(const float* __restrict__ s, unsigned short* __restrict__ d, int n4)
{
  int i = blockIdx.x * blockDim.x + threadIdx.x;
  int stride = gridDim.x * blockDim.x;
  for (; i < n4; i += stride) {
    float4 v = ((const float4*)s)[i];
    uint2 pk;
    pk.x = (unsigned)f2bf(v.x) | ((unsigned)f2bf(v.y) << 16);
    pk.y = (unsigned)f2bf(v.z) | ((unsigned)f2bf(v.w) << 16);
    ((uint2*)d)[i] = pk;
  }
}

// ---------------------------------------------------------------------------
// Weight transpose+convert: src fp32 (K x 128) -> dst bf16 (128 x K).
// ---------------------------------------------------------------------------
__global__ __launch_bounds__(256) void k_wt(
    const float* s0, const float* s1, const float* s2, const float* s3,
    const float* s4, const float* s5, const float* s6,
    unsigned short* d0, unsigned short* d1, unsigned short* d2, unsigned short* d3,
    unsigned short* d4, unsigned short* d5, unsigned short* d6)
{
  const float* srcs[7] = {s0, s1, s2, s3, s4, s5, s6};
  unsigned short* dsts[7] = {d0, d1, d2, d3, d4, d5, d6};
  const int Ks[7] = {64, 128, 128, 128, 128, 128, 256};
  int j = blockIdx.x;
  const float* s = srcs[j];
  unsigned short* d = dsts[j];
  int K = Ks[j];
  for (int idx = threadIdx.x; idx < K * 128; idx += 256) {
    int k = idx >> 7, n = idx & 127;
    d[n * K + k] = f2bf(s[idx]);
  }
}

// ---------------------------------------------------------------------------
// bf16 MFMA GEMM: Out(131072,128) = A @ W(KD,128) [+bias][relu]
//  Wt: bf16 transposed weights (128 x KD row-major).
//  AF32: A is fp32, converted to bf16 during LDS staging (else A is bf16).
//  BATCHW: A row = global_row & 511 (shared Ahat); Wt += batch*128*KD.
//  OMODE 0: bf16 row-major out, stride OS. 1: bf16 transposed-per-batch out
//  (Out[(b*128+c)*512+node]). 2: fp32 out stride 128 + fused LayerNorm.
// Block: GNT=4 consecutive 64-row tiles; W staged ONCE per block when KD<=128.
// ---------------------------------------------------------------------------
#define GNT 4
template<int KD, bool RELU, bool BATCHW, int OMODE, bool AF32>
__global__ __launch_bounds__(256) void k_bgemm(
    const void* __restrict__ Ap, const unsigned short* __restrict__ Wt,
    const float* __restrict__ bias, void* __restrict__ Out, int OS,
    const float* __restrict__ lng, const float* __restrict__ lnb)
{
  constexpr int KCH = (KD < 128) ? KD : 128;
  constexpr int STR = KCH + 8;
  constexpr bool WONCE = (KD <= 128);
  constexpr int ASH = (64 * STR > 8192) ? 64 * STR : 8192;   // shorts
  __shared__ short lds[ASH + 128 * STR];
  short* As = lds;
  short* Ws = lds + ASH;
  const unsigned short* Abf = (const unsigned short*)Ap;
  const float* Af = (const float*)Ap;
  const int t = threadIdx.x;
  const int wave = t >> 6, lane = t & 63;
  const int l15 = lane & 15, quad = lane >> 4;

  float bcol[8];
  #pragma unroll
  for (int nt = 0; nt < 8; nt++) bcol[nt] = bias ? bias[nt * 16 + l15] : 0.f;
  float gcol[8], bbcol[8];
  if (OMODE == 2) {
    #pragma unroll
    for (int nt = 0; nt < 8; nt++) { gcol[nt] = lng[nt * 16 + l15]; bbcol[nt] = lnb[nt * 16 + l15]; }
  }

  for (int g = blockIdx.x; g < (MROWS / 64) / GNT; g += gridDim.x) {
    if (WONCE) {
      const int b0 = (g * GNT * 64) >> 9;
      const unsigned short* Wb = BATCHW ? (Wt + (size_t)b0 * 128 * KD) : Wt;
      for (int i = t; i < 128 * (KCH / 8); i += 256) {
        int n = i / (KCH / 8), seg = i % (KCH / 8);
        *(short8v*)&Ws[n * STR + seg * 8] =
            *(const short8v*)&Wb[(size_t)n * KD + seg * 8];
      }
    }
    for (int tt = 0; tt < GNT; tt++) {
      const int tile = g * GNT + tt;
      const int rowbase = tile * 64;
      const int b = rowbase >> 9;
      float4v acc[8];
      #pragma unroll
      for (int nt = 0; nt < 8; nt++) acc[nt] = (float4v){0.f, 0.f, 0.f, 0.f};

      for (int kc = 0; kc < KD; kc += KCH) {
        __syncthreads();                       // protect prior reads of As/Ws/rep
        if (AF32) {
          for (int i = t; i < 64 * (KCH / 8); i += 256) {
            int r = i / (KCH / 8), seg = i % (KCH / 8);
            const float* sp = &Af[(size_t)(rowbase + r) * KD + kc + seg * 8];
            float4 fa = *(const float4*)sp;
            float4 fb = *(const float4*)(sp + 4);
            short8v pk;
            pk[0] = (short)f2bf(fa.x); pk[1] = (short)f2bf(fa.y);
            pk[2] = (short)f2bf(fa.z); pk[3] = (short)f2bf(fa.w);
            pk[4] = (short)f2bf(fb.x); pk[5] = (short)f2bf(fb.y);
            pk[6] = (short)f2bf(fb.z); pk[7] = (short)f2bf(fb.w);
            *(short8v*)&As[r * STR + seg * 8] = pk;
          }
        } else {
          for (int i = t; i < 64 * (KCH / 8); i += 256) {
            int r = i / (KCH / 8), seg = i % (KCH / 8);
            int arow = BATCHW ? ((rowbase & 511) + r) : (rowbase + r);
            *(short8v*)&As[r * STR + seg * 8] =
                *(const short8v*)&Abf[(size_t)arow * KD + kc + seg * 8];
          }
        }
        if (!WONCE) {
          const unsigned short* Wb = BATCHW ? (Wt + (size_t)b * 128 * KD) : Wt;
          for (int i = t; i < 128 * (KCH / 8); i += 256) {
            int n = i / (KCH / 8), seg = i % (KCH / 8);
            *(short8v*)&Ws[n * STR + seg * 8] =
                *(const short8v*)&Wb[(size_t)n * KD + kc + seg * 8];
          }
        }
        __syncthreads();
        #pragma unroll
        for (int k32 = 0; k32 < KCH / 32; k32++) {
          short8v af = *(const short8v*)&As[(wave * 16 + l15) * STR + k32 * 32 + quad * 8];
          #pragma unroll
          for (int nt = 0; nt < 8; nt++) {
            short8v wf = *(const short8v*)&Ws[(nt * 16 + l15) * STR + k32 * 32 + quad * 8];
            acc[nt] = __builtin_amdgcn_mfma_f32_16x16x32_bf16(af, wf, acc[nt], 0, 0, 0);
          }
        }
      }

      __syncthreads();                         // all waves done reading As/Ws
      if (OMODE == 0) {
        short* rep = As + wave * 2048;
        #pragma unroll
        for (int nt = 0; nt < 8; nt++)
          #pragma unroll
          for (int r = 0; r < 4; r++) {
            float v = acc[nt][r] + bcol[nt];
            if (RELU) v = fmaxf(v, 0.f);
            rep[(quad * 4 + r) * 128 + nt * 16 + l15] = (short)f2bf(v);
          }
        __syncthreads();
        unsigned short* Ob = (unsigned short*)Out;
        #pragma unroll
        for (int p = 0; p < 4; p++) {
          int row16 = (lane >> 4) + p * 4, seg = lane & 15;
          short8v vv = *(const short8v*)&rep[row16 * 128 + seg * 8];
          *(short8v*)&Ob[(size_t)(rowbase + wave * 16 + row16) * OS + seg * 8] = vv;
        }
      } else if (OMODE == 1) {
        short* rep = As + wave * 2048;         // [c:128][node:16]
        #pragma unroll
        for (int nt = 0; nt < 8; nt++)
          #pragma unroll
          for (int r = 0; r < 4; r++) {
            float v = acc[nt][r] + bcol[nt];
            if (RELU) v = fmaxf(v, 0.f);
            rep[(nt * 16 + l15) * 16 + quad * 4 + r] = (short)f2bf(v);
          }
        __syncthreads();
        unsigned short* Ob = (unsigned short*)Out;
        int node0 = (rowbase & 511) + wave * 16;
        #pragma unroll
        for (int p = 0; p < 4; p++) {
          int idx = p * 64 + lane, c = idx >> 1, half = idx & 1;
          short8v vv = *(const short8v*)&rep[c * 16 + half * 8];
          *(short8v*)&Ob[((size_t)(b * 128 + c)) * 512 + node0 + half * 8] = vv;
        }
      } else {
        float* repw = (float*)lds + wave * 2048;   // Ws chunk data dead here
        float vv[8][4];
        float s[4] = {0, 0, 0, 0}, ss[4] = {0, 0, 0, 0};
        #pragma unroll
        for (int nt = 0; nt < 8; nt++)
          #pragma unroll
          for (int r = 0; r < 4; r++) {
            float v = acc[nt][r] + bcol[nt];
            vv[nt][r] = v;
            s[r] += v; ss[r] += v * v;
          }
        #pragma unroll
        for (int r = 0; r < 4; r++) {
          s[r] += __shfl_xor(s[r], 1);  s[r] += __shfl_xor(s[r], 2);
          s[r] += __shfl_xor(s[r], 4);  s[r] += __shfl_xor(s[r], 8);
          ss[r] += __shfl_xor(ss[r], 1); ss[r] += __shfl_xor(ss[r], 2);
          ss[r] += __shfl_xor(ss[r], 4); ss[r] += __shfl_xor(ss[r], 8);
        }
        #pragma unroll
        for (int r = 0; r < 4; r++) {
          float mu = s[r] * (1.0f / 128.0f);
          float var = ss[r] * (1.0f / 128.0f) - mu * mu;
          float inv = rsqrtf(var + 1e-5f);
          #pragma unroll
          for (int nt = 0; nt < 8; nt++)
            repw[(quad * 4 + r) * 128 + nt * 16 + l15] =
                (vv[nt][r] - mu) * inv * gcol[nt] + bbcol[nt];
        }
        __syncthreads();
        float* Of = (float*)Out;
        #pragma unroll
        for (int p = 0; p < 8; p++) {
          int row16 = (lane >> 5) + p * 2, seg = lane & 31;
          float4 o = *(const float4*)&repw[row16 * 128 + seg * 4];
          *(float4*)&Of[(size_t)(rowbase + wave * 16 + row16) * 128 + seg * 4] = o;
        }
      }
    }
  }
}

// ---------------------------------------------------------------------------
// MFMA flash attention, FIXED m=0 (exact: softmax shift-invariance; |S|<<88).
// out = sum exp(S)*C*V / (sum exp(S)C + 1e-8 sum exp(S)).
// Per-lane sp/spc accumulators, one shuffle-reduce at kernel end.
// C read as bf16. Output bf16, row stride 256 (concat buffer col 0).
// NOTE: __syncthreads between P write and PV read is REQUIRED — without it
// the compiler may reorder the ds_read above the ds_write (round-5 NaN).
// ---------------------------------------------------------------------------
__global__ __launch_bounds__(256) void k_attn_mfma(
    const unsigned short* __restrict__ Qbf, const unsigned short* __restrict__ Kbf,
    const unsigned short* __restrict__ Vtbf, const unsigned short* __restrict__ CB,
    unsigned short* __restrict__ Ocb)
{
  const int b = blockIdx.x >> 3;
  const int qblk = blockIdx.x & 7;
  const int t = threadIdx.x;
  const int wave = t >> 6, lane = t & 63;
  const int l15 = lane & 15, quad = lane >> 4;
  const int q0w = qblk * 64 + wave * 16;

  __shared__ short Ksh[64 * 17 * 8];
  __shared__ short Vtsh[128 * 9 * 8];
  __shared__ short Psh[4 * 16 * 9 * 8];
  short* Pw = Psh + wave * (16 * 9 * 8);

  short8v qf[4];
  #pragma unroll
  for (int dc = 0; dc < 4; dc++)
    qf[dc] = *(const short8v*)&Qbf[((size_t)(b * NN + q0w + l15)) * HH + dc * 32 + quad * 8];

  float sp_r[4] = {0.f, 0.f, 0.f, 0.f}, spc_r[4] = {0.f, 0.f, 0.f, 0.f};
  float4v oacc[8];
  #pragma unroll
  for (int dn = 0; dn < 8; dn++) oacc[dn] = (float4v){0.f, 0.f, 0.f, 0.f};

  const float scale = 0.088388347648318447f;   // 1/sqrt(128)

  for (int kt = 0; kt < 8; kt++) {
    const int k0 = kt * 64;
    __syncthreads();
    for (int i = t; i < 64 * 16; i += 256) {
      int row = i >> 4, seg = i & 15;
      *(short8v*)&Ksh[(row * 17 + seg) * 8] =
          *(const short8v*)&Kbf[((size_t)(b * NN + k0 + row)) * HH + seg * 8];
    }
    for (int i = t; i < 128 * 8; i += 256) {
      int row = i >> 3, seg = i & 7;
      *(short8v*)&Vtsh[(row * 9 + seg) * 8] =
          *(const short8v*)&Vtbf[((size_t)(b * HH + row)) * NN + k0 + seg * 8];
    }
    __syncthreads();

    float cv[4][4];
    #pragma unroll
    for (int n = 0; n < 4; n++)
      #pragma unroll
      for (int r = 0; r < 4; r++)
        cv[n][r] = bf2f(CB[(size_t)(q0w + quad * 4 + r) * NN + k0 + n * 16 + l15]);

    float4v sacc[4];
    #pragma unroll
    for (int n = 0; n < 4; n++) {
      sacc[n] = (float4v){0.f, 0.f, 0.f, 0.f};
      #pragma unroll
      for (int dc = 0; dc < 4; dc++) {
        short8v kf = *(const short8v*)&Ksh[((n * 16 + l15) * 17 + dc * 4 + quad) * 8];
        sacc[n] = __builtin_amdgcn_mfma_f32_16x16x32_bf16(qf[dc], kf, sacc[n], 0, 0, 0);
      }
    }

    // p = exp(S), pc = p*C; accumulate per-lane, stage pc for PV MFMA
    #pragma unroll
    for (int n = 0; n < 4; n++)
      #pragma unroll
      for (int r = 0; r < 4; r++) {
        float p = __expf(sacc[n][r] * scale);
        float pcv = p * cv[n][r];
        sp_r[r] += p; spc_r[r] += pcv;
        Pw[(quad * 4 + r) * 72 + n * 16 + l15] = (short)f2bf(pcv);
      }
    __syncthreads();   // order P writes before A-fragment reads (compiler!)

    short8v pa[2];
    #pragma unroll
    for (int kc = 0; kc < 2; kc++)
      pa[kc] = *(const short8v*)&Pw[(l15 * 9 + kc * 4 + quad) * 8];
    #pragma unroll
    for (int dn = 0; dn < 8; dn++) {
      #pragma unroll
      for (int kc = 0; kc < 2; kc++) {
        short8v vf = *(const short8v*)&Vtsh[((dn * 16 + l15) * 9 + kc * 4 + quad) * 8];
        oacc[dn] = __builtin_amdgcn_mfma_f32_16x16x32_bf16(pa[kc], vf, oacc[dn], 0, 0, 0);
      }
    }
  }

  // final reduction over the 16 columns held across the quad's 16 lanes
  float inv[4];
  #pragma unroll
  for (int r = 0; r < 4; r++) {
    sp_r[r]  += __shfl_xor(sp_r[r], 1);  sp_r[r]  += __shfl_xor(sp_r[r], 2);
    sp_r[r]  += __shfl_xor(sp_r[r], 4);  sp_r[r]  += __shfl_xor(sp_r[r], 8);
    spc_r[r] += __shfl_xor(spc_r[r], 1); spc_r[r] += __shfl_xor(spc_r[r], 2);
    spc_r[r] += __shfl_xor(spc_r[r], 4); spc_r[r] += __shfl_xor(spc_r[r], 8);
    inv[r] = 1.0f / (spc_r[r] + 1e-8f * sp_r[r]);
  }
  #pragma unroll
  for (int dn = 0; dn < 8; dn++)
    #pragma unroll
    for (int r = 0; r < 4; r++)
      Ocb[((size_t)(b * NN + q0w + quad * 4 + r)) * 256 + dn * 16 + l15] =
          f2bf(oacc[dn][r] * inv[r]);
}

// ---------------------------------------------------------------------------
// ws layout: 5 x 33.5MB slots (A0,B0,C0,D0[2]) + AUX (AhatF 1MB, CB bf16
// 512KB, AhatB bf16 512KB, weights bf16 ~0.25MB). Vt bf16 overlays d_out's
// out region (scratch until the final fused-LN GEMM writes it).
// ---------------------------------------------------------------------------
extern "C" void kernel_launch(void* const* d_in, const int* in_sizes, int n_in,
                              void* d_out, int out_size, void* d_ws, size_t ws_size,
                              hipStream_t stream)
{
  const float* x     = (const float*)d_in[0];
  const int*   ei    = (const int*)d_in[1];
  const float* adj   = (const float*)d_in[2];
  const float* dmask = (const float*)d_in[3];
  const float* clog  = (const float*)d_in[4];
  const float* W_in  = (const float*)d_in[5];
  const float* b_in  = (const float*)d_in[6];
  const float* Wq    = (const float*)d_in[7];
  const float* bq    = (const float*)d_in[8];
  const float* Wk    = (const float*)d_in[9];
  const float* bk    = (const float*)d_in[10];
  const float* Wv    = (const float*)d_in[11];
  const float* bv    = (const float*)d_in[12];
  const float* gcnW  = (const float*)d_in[13];
  const float* gcnB  = (const float*)d_in[14];
  const float* Wf    = (const float*)d_in[15];
  const float* bf    = (const float*)d_in[16];
  const float* lng   = (const float*)d_in[17];
  const float* lnb   = (const float*)d_in[18];

  float* outp = (float*)d_out;
  float* Cmat = outp + OUT0;

  char* W = (char*)d_ws;
  const size_t SLOT = (size_t)MROWS * 128 * 2;       // 33,554,432 B
  unsigned short* A0 = (unsigned short*)(W);
  unsigned short* B0 = (unsigned short*)(W + SLOT);
  unsigned short* C0 = (unsigned short*)(W + 2 * SLOT);
  unsigned short* D0 = (unsigned short*)(W + 3 * SLOT);   // 2*SLOT bytes
  char* AUX = W + 5 * SLOT;
  float*          AhatF = (float*)AUX;                    // 512*512 fp32
  unsigned short* CBm   = (unsigned short*)(AUX + 512 * 512 * 4);
  unsigned short* AhatB = CBm + 512 * 512;
  unsigned short* WB    = AhatB + 512 * 512;
  unsigned short* W_int = WB;            // 128x64
  unsigned short* Wqt   = WB + 8192;     // 128x128
  unsigned short* Wkt   = Wqt + 16384;
  unsigned short* Wvt   = Wkt + 16384;
  unsigned short* G0t   = Wvt + 16384;
  unsigned short* G1t   = G0t + 16384;
  unsigned short* Wft   = G1t + 16384;   // 128x256

  unsigned short* Vtbf = (unsigned short*)outp;      // scratch until fuse GEMM

  // --- prep ---
  k_causalC<<<512, 256, 0, stream>>>(clog, adj, dmask, Cmat, CBm);
  k_ahat<<<1, 512, 0, stream>>>(ei, AhatF);
  k_f2b<<<256, 256, 0, stream>>>(AhatF, AhatB, 512 * 512 / 4);
  k_wt<<<7, 256, 0, stream>>>(W_in, Wq, Wk, Wv, gcnW, gcnW + HH * HH, Wf,
                              W_int, Wqt, Wkt, Wvt, G0t, G1t, Wft);

  // --- h = relu(x @ W_in + b_in) -> B0 (x converted in-staging) ---
  k_bgemm<64, true, false, 0, true><<<512, 256, 0, stream>>>(
      x, W_int, b_in, B0, 128, nullptr, nullptr);
  // --- GCN layer 0: hWt -> C0 ; g1 = relu(Ahat@hW + b0) -> A0 ---
  k_bgemm<128, false, false, 1, false><<<512, 256, 0, stream>>>(
      B0, G0t, nullptr, C0, 0, nullptr, nullptr);
  k_bgemm<512, true, true, 0, false><<<512, 256, 0, stream>>>(
      AhatB, C0, gcnB, A0, 128, nullptr, nullptr);
  // --- GCN layer 1: hWt -> C0 ; g2 -> D0 col 128 (stride 256) ---
  k_bgemm<128, false, false, 1, false><<<512, 256, 0, stream>>>(
      A0, G1t, nullptr, C0, 0, nullptr, nullptr);
  k_bgemm<512, true, true, 0, false><<<512, 256, 0, stream>>>(
      AhatB, C0, gcnB + HH, D0 + 128, 256, nullptr, nullptr);
  // --- Q -> C0, K -> A0, Vt -> outp ---
  k_bgemm<128, false, false, 0, false><<<512, 256, 0, stream>>>(
      B0, Wqt, bq, C0, 128, nullptr, nullptr);
  k_bgemm<128, false, false, 0, false><<<512, 256, 0, stream>>>(
      B0, Wkt, bk, A0, 128, nullptr, nullptr);
  k_bgemm<128, false, false, 1, false><<<512, 256, 0, stream>>>(
      B0, Wvt, bv, Vtbf, 0, nullptr, nullptr);
  // --- attention -> D0 col 0 (stride 256) ---
  k_attn_mfma<<<BB * 8, 256, 0, stream>>>(C0, A0, Vtbf, CBm, D0);
  // --- fuse + fused LayerNorm -> outp ---
  k_bgemm<256, false, false, 2, false><<<512, 256, 0, stream>>>(
      D0, Wft, bf, outp, 128, lng, lnb);
}